// Round 2
// baseline (180.306 us; speedup 1.0000x reference)
//
#include <hip/hip_runtime.h>
#include <hip/hip_bf16.h>

#define GBM 128
#define GBN 128
#define GBK 16

#define CHUNK 32
#define MAXC 512

// ---------------------------------------------------------------------------
// Edge-index layout detection: reference dtype is int64; if int64 (values
// < 2^31) every odd int32 word is 0. flag==1 => int32 layout.
// ---------------------------------------------------------------------------
__global__ void detect_i64_kernel(const int* __restrict__ e, int E, int* __restrict__ flag) {
    int i = blockIdx.x * blockDim.x + threadIdx.x;
    int acc = 0;
    for (; i < E; i += gridDim.x * blockDim.x) acc |= e[2 * i + 1];
    if (acc) atomicOr(flag, 1);
}

// Scatter edges into dense row-major bitmask [N][N/32]. atomicOr dedups
// (idempotent -> deterministic regardless of scheduling).
__global__ void scatter_edges_kernel(const int* __restrict__ e, int E, int N,
                                     unsigned* __restrict__ mask,
                                     const int* __restrict__ flag) {
    bool i32mode = (*flag != 0);
    int i = blockIdx.x * blockDim.x + threadIdx.x;
    int nw = N >> 5;
    for (; i < E; i += gridDim.x * blockDim.x) {
        int row, col;
        if (i32mode) { row = e[i];     col = e[E + i]; }
        else         { row = e[2 * i]; col = e[2 * E + 2 * i]; }
        if ((unsigned)row < (unsigned)N && (unsigned)col < (unsigned)N)
            atomicOr(&mask[(size_t)row * nw + (col >> 5)], 1u << (col & 31));
    }
}

// ---------------------------------------------------------------------------
// fp32 GEMM-NT: C[m,n] = sum_k A'[m,k] * W[n,k] + bias[n]
// A' = virtual concat [A | A2] split at k=256 (both row stride 256).
// 128x128 tile, BK=16, 256 threads, 8x8 microtile.
// LDS k-major (As[k][m]) so the inner loop does float4 LDS reads.
// ---------------------------------------------------------------------------
__device__ __forceinline__ void gemm_body(
    const float* __restrict__ A, const float* __restrict__ A2,
    const float* __restrict__ W, const float* __restrict__ bias,
    float* __restrict__ C, int m0, int n0, int K, int ldw)
{
    __shared__ float As[GBK][GBM + 4];
    __shared__ float Bs[GBK][GBN + 4];
    int t  = threadIdx.x;
    int tx = t & 15;     // output col group (8 cols)
    int ty = t >> 4;     // output row group (8 rows)
    float acc[8][8] = {{0.f}};

    for (int k0 = 0; k0 < K; k0 += GBK) {
        const float* Ap = (k0 < 256) ? A : A2;
        int kc = k0 & 255;
        #pragma unroll
        for (int i = 0; i < 2; i++) {
            int s = t + (i << 8);           // 0..511 float4 slots
            int r = s >> 2;                 // 0..127 row in tile
            int c = (s & 3) << 2;           // 0,4,8,12 k offset
            float4 a = *(const float4*)&Ap[(size_t)(m0 + r) * 256 + kc + c];
            As[c + 0][r] = a.x;  As[c + 1][r] = a.y;
            As[c + 2][r] = a.z;  As[c + 3][r] = a.w;
            float4 w4 = *(const float4*)&W[(size_t)(n0 + r) * ldw + k0 + c];
            Bs[c + 0][r] = w4.x; Bs[c + 1][r] = w4.y;
            Bs[c + 2][r] = w4.z; Bs[c + 3][r] = w4.w;
        }
        __syncthreads();
        #pragma unroll
        for (int kk = 0; kk < GBK; kk++) {
            float av[8], bw[8];
            *(float4*)&av[0] = *(const float4*)&As[kk][(ty << 3) + 0];
            *(float4*)&av[4] = *(const float4*)&As[kk][(ty << 3) + 4];
            *(float4*)&bw[0] = *(const float4*)&Bs[kk][(tx << 3) + 0];
            *(float4*)&bw[4] = *(const float4*)&Bs[kk][(tx << 3) + 4];
            #pragma unroll
            for (int i = 0; i < 8; i++)
                #pragma unroll
                for (int j = 0; j < 8; j++)
                    acc[i][j] = fmaf(av[i], bw[j], acc[i][j]);
        }
        __syncthreads();
    }

    #pragma unroll
    for (int i = 0; i < 8; i++) {
        int row  = m0 + (ty << 3) + i;
        int colb = n0 + (tx << 3);
        float4 o1, o2;
        o1.x = acc[i][0] + bias[colb + 0];
        o1.y = acc[i][1] + bias[colb + 1];
        o1.z = acc[i][2] + bias[colb + 2];
        o1.w = acc[i][3] + bias[colb + 3];
        o2.x = acc[i][4] + bias[colb + 4];
        o2.y = acc[i][5] + bias[colb + 5];
        o2.z = acc[i][6] + bias[colb + 6];
        o2.w = acc[i][7] + bias[colb + 7];
        *(float4*)&C[(size_t)row * 256 + colb + 0] = o1;
        *(float4*)&C[(size_t)row * 256 + colb + 4] = o2;
    }
}

__global__ __launch_bounds__(256) void qkv_gemm_kernel(
    const float* __restrict__ x,
    const float* __restrict__ Wq, const float* __restrict__ bq,
    const float* __restrict__ Wk, const float* __restrict__ bk,
    const float* __restrict__ Wv, const float* __restrict__ bv,
    float* __restrict__ q, float* __restrict__ k, float* __restrict__ v)
{
    int by = blockIdx.y;
    int which = by >> 1;                 // 0=q 1=k 2=v
    int n0 = (by & 1) * GBN;
    const float* W = (which == 0) ? Wq : (which == 1) ? Wk : Wv;
    const float* b = (which == 0) ? bq : (which == 1) ? bk : bv;
    float*       C = (which == 0) ? q  : (which == 1) ? k  : v;
    gemm_body(x, x, W, b, C, blockIdx.x * GBM, n0, 256, 256);
}

__global__ __launch_bounds__(256) void final_gemm_kernel(
    const float* __restrict__ x, const float* __restrict__ y,
    const float* __restrict__ Wp, const float* __restrict__ bp,
    float* __restrict__ out)
{
    gemm_body(x, y, Wp, bp, out, blockIdx.x * GBM, blockIdx.y * GBN, 512, 512);
}

// ---------------------------------------------------------------------------
// Sparse masked attention, chunk-parallel two-phase softmax.
// One block per query row. Roles:
//   compact:  waves 0/1 scan 128 mask words (wave shfl scan, 2 syncs)
//   stage:    all 256 threads stage <=32 K rows to LDS (coalesced float4)
//   scores:   thread (h=t>>5, jl=t&31) computes one full 32-dot from LDS
//   merge:    per-32-lane-group chunk max/sum (10 shfl + 2 exp per CHUNK)
//   V accum:  thread (h, d) coalesced gather of V rows weighted by ws[h][j]
// ---------------------------------------------------------------------------
__global__ __launch_bounds__(256) void attn_kernel(
    const unsigned* __restrict__ mask,
    const float* __restrict__ q, const float* __restrict__ k,
    const float* __restrict__ v, float* __restrict__ y, int N)
{
    __shared__ int   cols[MAXC];
    __shared__ float qs[256];
    __shared__ float Ks[CHUNK][260];   // 260: float4-aligned rows
    __shared__ float ws[8][CHUNK];
    __shared__ int   wtot[2];

    int n    = blockIdx.x;
    int t    = threadIdx.x;
    int lane = t & 63;
    int wv   = t >> 6;
    int nw   = N >> 5;                  // 128 mask words per row

    // ---- compact mask row (deterministic, sorted) ----
    unsigned word = 0; int pc = 0;
    if (t < nw) { word = mask[(size_t)n * nw + t]; pc = __popc(word); }
    int scan = pc;
    #pragma unroll
    for (int o = 1; o < 64; o <<= 1) {
        int other = __shfl_up(scan, o, 64);
        if (lane >= o) scan += other;
    }
    if (wv < 2 && lane == 63) wtot[wv] = scan;
    qs[t] = q[(size_t)n * 256 + t];
    __syncthreads();
    if (t < nw) {
        int off = (wv == 1 ? wtot[0] : 0) + scan - pc;
        unsigned w = word;
        while (w && off < MAXC) {
            int b = __ffs(w) - 1;
            w &= w - 1;
            cols[off++] = (t << 5) + b;
        }
    }
    int cnt = wtot[0] + wtot[1];
    if (cnt > MAXC) cnt = MAXC;
    __syncthreads();

    const float scale = 0.17677669529663687f;  // 1/sqrt(32)
    int h  = t >> 5;
    int jl = t & 31;
    float mx = -1e30f, l = 0.f, acc = 0.f;

    for (int c0 = 0; c0 < cnt; c0 += CHUNK) {
        int cc = min(CHUNK, cnt - c0);
        // stage K rows (coalesced: 4-lane clusters read 64B contiguous)
        for (int s = t; s < (cc << 6); s += 256) {
            int jr = s >> 6;
            int c4 = (s & 63) << 2;
            float4 kv = *(const float4*)&k[(size_t)cols[c0 + jr] * 256 + c4];
            *(float4*)&Ks[jr][c4] = kv;
        }
        __syncthreads();

        // scores: one (h, j) dot product per thread, no shuffles
        float s_val = -1e30f;
        if (jl < cc) {
            float sa = 0.f;
            #pragma unroll
            for (int d4 = 0; d4 < 8; d4++) {
                float4 k4 = *(const float4*)&Ks[jl][(h << 5) + (d4 << 2)];
                float4 q4 = *(const float4*)&qs[(h << 5) + (d4 << 2)];
                sa = fmaf(k4.x, q4.x, sa);
                sa = fmaf(k4.y, q4.y, sa);
                sa = fmaf(k4.z, q4.z, sa);
                sa = fmaf(k4.w, q4.w, sa);
            }
            s_val = sa * scale;
        }
        // chunk-level online softmax merge within each 32-lane head group
        float cm = s_val;
        #pragma unroll
        for (int o = 16; o > 0; o >>= 1) cm = fmaxf(cm, __shfl_xor(cm, o, 32));
        float mnew = fmaxf(mx, cm);
        float f = __expf(mx - mnew);
        float w = (jl < cc) ? __expf(s_val - mnew) : 0.f;
        float lsum = w;
        #pragma unroll
        for (int o = 16; o > 0; o >>= 1) lsum += __shfl_xor(lsum, o, 32);
        l  = l * f + lsum;
        mx = mnew;
        ws[h][jl] = w;
        __syncthreads();

        // V accumulation: coalesced row gather, weights broadcast from LDS
        acc *= f;
        int j = 0;
        for (; j + 2 <= cc; j += 2) {
            float v0 = v[(size_t)cols[c0 + j + 0] * 256 + t];
            float v1 = v[(size_t)cols[c0 + j + 1] * 256 + t];
            acc = fmaf(ws[h][j + 0], v0, acc);
            acc = fmaf(ws[h][j + 1], v1, acc);
        }
        if (j < cc)
            acc = fmaf(ws[h][j], v[(size_t)cols[c0 + j] * 256 + t], acc);
        __syncthreads();   // protect Ks/ws before next chunk
    }

    y[(size_t)n * 256 + t] = (cnt > 0) ? acc / l : 0.f;
}

// ---------------------------------------------------------------------------
extern "C" void kernel_launch(void* const* d_in, const int* in_sizes, int n_in,
                              void* d_out, int out_size, void* d_ws, size_t ws_size,
                              hipStream_t stream) {
    const float* x  = (const float*)d_in[0];
    const int*   ei = (const int*)d_in[1];
    const float* Wq = (const float*)d_in[2];
    const float* bq = (const float*)d_in[3];
    const float* Wk = (const float*)d_in[4];
    const float* bk = (const float*)d_in[5];
    const float* Wv = (const float*)d_in[6];
    const float* bv = (const float*)d_in[7];
    const float* Wp = (const float*)d_in[8];
    const float* bp = (const float*)d_in[9];
    float* out = (float*)d_out;

    const int D = 256;
    int N = in_sizes[0] / D;       // 4096
    int E = in_sizes[1] / 2;       // 135168 edges (incl. self loops)

    size_t maskB = (size_t)N * (N >> 5) * sizeof(unsigned);   // 2 MB
    char* ws = (char*)d_ws;
    unsigned* mask = (unsigned*)ws;
    int* flag = (int*)(ws + maskB);
    float* q = (float*)(ws + maskB + 256);
    float* k = q + (size_t)N * D;
    float* v = k + (size_t)N * D;
    float* y = v + (size_t)N * D;

    hipMemsetAsync(ws, 0, maskB + 256, stream);
    detect_i64_kernel<<<256, 256, 0, stream>>>(ei, E, flag);
    scatter_edges_kernel<<<256, 256, 0, stream>>>(ei, E, N, mask, flag);

    dim3 gq(N / GBM, 6);
    qkv_gemm_kernel<<<gq, 256, 0, stream>>>(x, Wq, bq, Wk, bk, Wv, bv, q, k, v);

    attn_kernel<<<N, 256, 0, stream>>>(mask, q, k, v, y, N);

    dim3 gf(N / GBM, 2);
    final_gemm_kernel<<<gf, 256, 0, stream>>>(x, y, Wp, bp, out);
}

// Round 3
// 92.915 us; speedup vs baseline: 1.9405x; 1.9405x over previous
//
#include <hip/hip_runtime.h>
#include <hip/hip_bf16.h>

typedef unsigned short u16;
typedef __attribute__((ext_vector_type(8))) short short8;   // 8 bf16 = 4 VGPR
typedef __attribute__((ext_vector_type(4))) float f32x4;

__device__ __forceinline__ float b2f(u16 b) {
    return __uint_as_float(((unsigned)b) << 16);
}

#define CHUNK 32
#define MAXC 512

// ---------------------------------------------------------------------------
// Edge-index layout detection (int64 ref dtype: odd int32 words all zero).
// ---------------------------------------------------------------------------
__global__ void detect_i64_kernel(const int* __restrict__ e, int E, int* __restrict__ flag) {
    int i = blockIdx.x * blockDim.x + threadIdx.x;
    int acc = 0;
    for (; i < E; i += gridDim.x * blockDim.x) acc |= e[2 * i + 1];
    if (acc) atomicOr(flag, 1);
}

// Dense bitmask scatter; atomicOr dedups (idempotent -> deterministic).
__global__ void scatter_edges_kernel(const int* __restrict__ e, int E, int N,
                                     unsigned* __restrict__ mask,
                                     const int* __restrict__ flag) {
    bool i32mode = (*flag != 0);
    int i = blockIdx.x * blockDim.x + threadIdx.x;
    int nw = N >> 5;
    for (; i < E; i += gridDim.x * blockDim.x) {
        int row, col;
        if (i32mode) { row = e[i];     col = e[E + i]; }
        else         { row = e[2 * i]; col = e[2 * E + 2 * i]; }
        if ((unsigned)row < (unsigned)N && (unsigned)col < (unsigned)N)
            atomicOr(&mask[(size_t)row * nw + (col >> 5)], 1u << (col & 31));
    }
}

// ---------------------------------------------------------------------------
// fp32 -> bf16 conversion: x (1M), Wq|Wk|Wv fused (192K), Wp (128K) elems.
// i indexes float4 groups; boundaries are all float4-aligned.
// ---------------------------------------------------------------------------
__global__ __launch_bounds__(256) void convert_kernel(
    const float* __restrict__ x,
    const float* __restrict__ Wq, const float* __restrict__ Wk,
    const float* __restrict__ Wv, const float* __restrict__ Wp,
    __hip_bfloat16* __restrict__ xb, __hip_bfloat16* __restrict__ wqkvb,
    __hip_bfloat16* __restrict__ wpb)
{
    int i = blockIdx.x * blockDim.x + threadIdx.x;   // 0 .. 344063
    const float4* src; __hip_bfloat16* dst;
    int j = i - 262144;
    if (i < 262144)      { src = (const float4*)x  + i;          dst = xb    + 4 * (size_t)i; }
    else if (j < 16384)  { src = (const float4*)Wq + j;          dst = wqkvb + 4 * (size_t)j; }
    else if (j < 32768)  { src = (const float4*)Wk + (j - 16384); dst = wqkvb + 4 * (size_t)j; }
    else if (j < 49152)  { src = (const float4*)Wv + (j - 32768); dst = wqkvb + 4 * (size_t)j; }
    else                 { src = (const float4*)Wp + (j - 49152); dst = wpb   + 4 * (size_t)(j - 49152); }
    float4 f = *src;
    dst[0] = __float2bfloat16(f.x);
    dst[1] = __float2bfloat16(f.y);
    dst[2] = __float2bfloat16(f.z);
    dst[3] = __float2bfloat16(f.w);
}

// ---------------------------------------------------------------------------
// QKV MFMA GEMM: [4096 x 256] bf16 @ Wqkv^T [768 x 256] bf16 -> q|k|v bf16.
// Block = 4 waves; wave = 32 rows x 64 cols (2 A-frags x 4 B-frags).
// No LDS: operands are L2-resident; fragments loaded lane-direct.
//   A-frag: lane l, elem i -> A[l&15][8*(l>>4)+i]   (16B contiguous per lane)
//   B-frag: lane l, elem i -> W[n + (l&15)][8*(l>>4)+i]
//   D:      lane l, reg  r -> D[4*(l>>4)+r][l&15]
// ---------------------------------------------------------------------------
__global__ __launch_bounds__(256) void qkv_mfma_kernel(
    const __hip_bfloat16* __restrict__ xb,
    const __hip_bfloat16* __restrict__ wqkvb,
    const float* __restrict__ bq, const float* __restrict__ bk,
    const float* __restrict__ bv,
    __hip_bfloat16* __restrict__ q, __hip_bfloat16* __restrict__ k,
    __hip_bfloat16* __restrict__ v)
{
    int t  = threadIdx.x;
    int wv = t >> 6, l = t & 63, lr = l & 15, lk = l >> 4;
    int m0  = blockIdx.x * 128 + wv * 32;
    int n0f = blockIdx.y * 64;                   // fused col base (0..704)

    f32x4 acc[2][4] = {};
    const short8* a0p = (const short8*)(xb + (size_t)(m0 + lr) * 256 + lk * 8);
    const short8* a1p = (const short8*)(xb + (size_t)(m0 + 16 + lr) * 256 + lk * 8);
    const short8* wp_ = (const short8*)(wqkvb + (size_t)(n0f + lr) * 256 + lk * 8);

    #pragma unroll
    for (int kk = 0; kk < 8; kk++) {
        short8 a0 = a0p[kk * 4];                 // +32 bf16 per k-step = 4 short8
        short8 a1 = a1p[kk * 4];
        #pragma unroll
        for (int j = 0; j < 4; j++) {
            short8 b = wp_[(size_t)j * 16 * 32 + kk * 4];   // +16 rows = 16*256 bf16
            acc[0][j] = __builtin_amdgcn_mfma_f32_16x16x32_bf16(a0, b, acc[0][j], 0, 0, 0);
            acc[1][j] = __builtin_amdgcn_mfma_f32_16x16x32_bf16(a1, b, acc[1][j], 0, 0, 0);
        }
    }

    int which = n0f >> 8;                        // 0=q 1=k 2=v (64|256 alignment)
    int ncl   = n0f & 255;
    const float* bias = (which == 0) ? bq : (which == 1) ? bk : bv;
    __hip_bfloat16* T = (which == 0) ? q  : (which == 1) ? k  : v;

    #pragma unroll
    for (int i2 = 0; i2 < 2; i2++)
        #pragma unroll
        for (int j = 0; j < 4; j++)
            #pragma unroll
            for (int r = 0; r < 4; r++) {
                int grow = m0 + i2 * 16 + lk * 4 + r;
                int gc   = ncl + j * 16 + lr;
                T[(size_t)grow * 256 + gc] = __float2bfloat16(acc[i2][j][r] + bias[gc]);
            }
}

// ---------------------------------------------------------------------------
// Final MFMA GEMM: out = [xb | yb] @ Wp^T + bp, K=512, fp32 out.
// Block = 4 waves; wave = 16 rows x 64 cols. Grid (64, 4) = 256 blocks.
// ---------------------------------------------------------------------------
__global__ __launch_bounds__(256) void final_mfma_kernel(
    const __hip_bfloat16* __restrict__ xb, const __hip_bfloat16* __restrict__ yb,
    const __hip_bfloat16* __restrict__ wpb, const float* __restrict__ bp,
    float* __restrict__ out)
{
    int t  = threadIdx.x;
    int wv = t >> 6, l = t & 63, lr = l & 15, lk = l >> 4;
    int m0 = blockIdx.x * 64 + wv * 16;
    int n0 = blockIdx.y * 64;

    f32x4 acc[4] = {};
    const short8* axp = (const short8*)(xb + (size_t)(m0 + lr) * 256 + lk * 8);
    const short8* ayp = (const short8*)(yb + (size_t)(m0 + lr) * 256 + lk * 8);
    const short8* wp_ = (const short8*)(wpb + (size_t)(n0 + lr) * 512 + lk * 8);

    #pragma unroll
    for (int kk = 0; kk < 16; kk++) {
        short8 a = (kk < 8) ? axp[kk * 4] : ayp[(kk - 8) * 4];
        #pragma unroll
        for (int j = 0; j < 4; j++) {
            short8 b = wp_[(size_t)j * 16 * 64 + kk * 4];   // +16 rows = 16*512 bf16
            acc[j] = __builtin_amdgcn_mfma_f32_16x16x32_bf16(a, b, acc[j], 0, 0, 0);
        }
    }

    #pragma unroll
    for (int j = 0; j < 4; j++)
        #pragma unroll
        for (int r = 0; r < 4; r++) {
            int grow = m0 + lk * 4 + r;
            int gc   = n0 + j * 16 + lr;
            out[(size_t)grow * 256 + gc] = acc[j][r] + bp[gc];
        }
}

// ---------------------------------------------------------------------------
// Sparse masked attention, bf16 K/V/Q, zero in-loop syncthreads.
// One block / query row. Threads: (h = t>>5, jl = t&31).
//   compact: 128 mask words -> sorted col list (wave shfl scan, 2 syncs total)
//   scores:  thread (h, jl) computes full 32-dot for neighbor jl from global
//            (kb L2-resident; 4x 16B loads); chunk online-softmax merge via
//            width-32 shuffles; weight kept in REGISTER
//   V accum: thread (h, d=jl): w broadcast via __shfl(w, j, 32) -- no LDS
// ---------------------------------------------------------------------------
__global__ __launch_bounds__(256) void attn_kernel(
    const unsigned* __restrict__ mask,
    const u16* __restrict__ qb, const u16* __restrict__ kb,
    const u16* __restrict__ vb, __hip_bfloat16* __restrict__ yb, int N)
{
    __shared__ int cols[MAXC];
    __shared__ int wtot[2];

    int n    = blockIdx.x;
    int t    = threadIdx.x;
    int lane = t & 63;
    int wv   = t >> 6;
    int nw   = N >> 5;                  // 128

    // ---- compact mask row (deterministic, sorted) ----
    unsigned word = 0; int pc = 0;
    if (t < nw) { word = mask[(size_t)n * nw + t]; pc = __popc(word); }
    int scan = pc;
    #pragma unroll
    for (int o = 1; o < 64; o <<= 1) {
        int other = __shfl_up(scan, o, 64);
        if (lane >= o) scan += other;
    }
    if (wv < 2 && lane == 63) wtot[wv] = scan;
    __syncthreads();
    if (t < nw) {
        int off = (wv == 1 ? wtot[0] : 0) + scan - pc;
        unsigned w = word;
        while (w && off < MAXC) {
            int b = __ffs(w) - 1;
            w &= w - 1;
            cols[off++] = (t << 5) + b;
        }
    }
    int cnt = wtot[0] + wtot[1];
    if (cnt > MAXC) cnt = MAXC;
    __syncthreads();

    int h  = t >> 5;
    int jl = t & 31;

    // q for this head into registers (exact bf16->f32)
    float qreg[32];
    const short8* qp = (const short8*)(qb + (size_t)n * 256 + h * 32);
    #pragma unroll
    for (int i = 0; i < 4; i++) {
        short8 s = qp[i];
        #pragma unroll
        for (int e = 0; e < 8; e++) qreg[i * 8 + e] = b2f((u16)s[e]);
    }

    const float scale = 0.17677669529663687f;   // 1/sqrt(32)
    float mx = -1e30f, lsm = 0.f, acc = 0.f;

    for (int c0 = 0; c0 < cnt; c0 += CHUNK) {
        int cc = min(CHUNK, cnt - c0);
        // --- score for neighbor jl of this chunk ---
        float s_val = -1e30f;
        if (jl < cc) {
            int col = cols[c0 + jl];
            const short8* kp = (const short8*)(kb + (size_t)col * 256 + h * 32);
            float sa = 0.f;
            #pragma unroll
            for (int i = 0; i < 4; i++) {
                short8 s = kp[i];
                #pragma unroll
                for (int e = 0; e < 8; e++)
                    sa = fmaf(b2f((u16)s[e]), qreg[i * 8 + e], sa);
            }
            s_val = sa * scale;
        }
        // --- chunk-level online softmax merge (width-32 group) ---
        float cm = s_val;
        #pragma unroll
        for (int o = 16; o > 0; o >>= 1) cm = fmaxf(cm, __shfl_xor(cm, o, 32));
        float mnew = fmaxf(mx, cm);
        float f = __expf(mx - mnew);
        float w = (jl < cc) ? __expf(s_val - mnew) : 0.f;
        float ls = w;
        #pragma unroll
        for (int o = 16; o > 0; o >>= 1) ls += __shfl_xor(ls, o, 32);
        lsm = lsm * f + ls;
        mx  = mnew;

        // --- V accumulation: w broadcast by shuffle, coalesced bf16 reads ---
        acc *= f;
        int j = 0;
        for (; j + 4 <= cc; j += 4) {
            float v0 = b2f(vb[(size_t)cols[c0 + j + 0] * 256 + t]);
            float v1 = b2f(vb[(size_t)cols[c0 + j + 1] * 256 + t]);
            float v2 = b2f(vb[(size_t)cols[c0 + j + 2] * 256 + t]);
            float v3 = b2f(vb[(size_t)cols[c0 + j + 3] * 256 + t]);
            acc = fmaf(__shfl(w, j + 0, 32), v0, acc);
            acc = fmaf(__shfl(w, j + 1, 32), v1, acc);
            acc = fmaf(__shfl(w, j + 2, 32), v2, acc);
            acc = fmaf(__shfl(w, j + 3, 32), v3, acc);
        }
        for (; j < cc; j++)
            acc = fmaf(__shfl(w, j, 32), b2f(vb[(size_t)cols[c0 + j] * 256 + t]), acc);
    }

    yb[(size_t)n * 256 + t] = __float2bfloat16((cnt > 0) ? acc / lsm : 0.f);
}

// ---------------------------------------------------------------------------
extern "C" void kernel_launch(void* const* d_in, const int* in_sizes, int n_in,
                              void* d_out, int out_size, void* d_ws, size_t ws_size,
                              hipStream_t stream) {
    const float* x  = (const float*)d_in[0];
    const int*   ei = (const int*)d_in[1];
    const float* Wq = (const float*)d_in[2];
    const float* bq = (const float*)d_in[3];
    const float* Wk = (const float*)d_in[4];
    const float* bk = (const float*)d_in[5];
    const float* Wv = (const float*)d_in[6];
    const float* bv = (const float*)d_in[7];
    const float* Wp = (const float*)d_in[8];
    const float* bp = (const float*)d_in[9];
    float* out = (float*)d_out;

    const int D = 256;
    int N = in_sizes[0] / D;       // 4096
    int E = in_sizes[1] / 2;       // 135168

    size_t maskB = (size_t)N * (N >> 5) * sizeof(unsigned);   // 2 MB
    char* ws = (char*)d_ws;
    unsigned* mask = (unsigned*)ws;
    int* flag = (int*)(ws + maskB);
    __hip_bfloat16* xb    = (__hip_bfloat16*)(ws + maskB + 256);
    __hip_bfloat16* qbb   = xb  + (size_t)N * D;
    __hip_bfloat16* kbb   = qbb + (size_t)N * D;
    __hip_bfloat16* vbb   = kbb + (size_t)N * D;
    __hip_bfloat16* ybb   = vbb + (size_t)N * D;
    __hip_bfloat16* wqkvb = ybb + (size_t)N * D;
    __hip_bfloat16* wpb   = wqkvb + 768 * 256;

    hipMemsetAsync(ws, 0, maskB + 256, stream);
    detect_i64_kernel<<<256, 256, 0, stream>>>(ei, E, flag);
    scatter_edges_kernel<<<256, 256, 0, stream>>>(ei, E, N, mask, flag);

    convert_kernel<<<1344, 256, 0, stream>>>(x, Wq, Wk, Wv, Wp, xb, wqkvb, wpb);

    dim3 gq(N / 128, 12);
    qkv_mfma_kernel<<<gq, 256, 0, stream>>>(xb, wqkvb, bq, bk, bv, qbb, kbb, vbb);

    attn_kernel<<<N, 256, 0, stream>>>(mask, (const u16*)qbb, (const u16*)kbb,
                                       (const u16*)vbb, ybb, N);

    dim3 gf(N / 64, 4);
    final_mfma_kernel<<<gf, 256, 0, stream>>>(xb, ybb, wpb, bp, out);
}

// Round 4
// 92.422 us; speedup vs baseline: 1.9509x; 1.0053x over previous
//
#include <hip/hip_runtime.h>
#include <hip/hip_bf16.h>

typedef unsigned short u16;
typedef __attribute__((ext_vector_type(8))) short short8;   // 8 bf16 = 4 VGPR
typedef __attribute__((ext_vector_type(4))) float f32x4;

__device__ __forceinline__ float b2f(u16 b) {
    return __uint_as_float(((unsigned)b) << 16);
}

#define CHUNK 32
#define MAXC 512

// ---------------------------------------------------------------------------
// Fast workspace clear (mask + flag). The HIP runtime's fillBufferAligned for
// this 2MB+256B memset ran at 48 GB/s (~43us, half the kernel total!) -- a
// grid-stride uint4 store kernel runs at store BW instead.
// ---------------------------------------------------------------------------
__global__ __launch_bounds__(256) void clear_kernel(uint4* __restrict__ p, int n16) {
    int i = blockIdx.x * blockDim.x + threadIdx.x;
    uint4 z = {0u, 0u, 0u, 0u};
    for (; i < n16; i += gridDim.x * blockDim.x) p[i] = z;
}

// ---------------------------------------------------------------------------
// Edge-index layout detection (int64 ref dtype: odd int32 words all zero).
// ---------------------------------------------------------------------------
__global__ void detect_i64_kernel(const int* __restrict__ e, int E, int* __restrict__ flag) {
    int i = blockIdx.x * blockDim.x + threadIdx.x;
    int acc = 0;
    for (; i < E; i += gridDim.x * blockDim.x) acc |= e[2 * i + 1];
    if (acc) atomicOr(flag, 1);
}

// Dense bitmask scatter; atomicOr dedups (idempotent -> deterministic).
__global__ void scatter_edges_kernel(const int* __restrict__ e, int E, int N,
                                     unsigned* __restrict__ mask,
                                     const int* __restrict__ flag) {
    bool i32mode = (*flag != 0);
    int i = blockIdx.x * blockDim.x + threadIdx.x;
    int nw = N >> 5;
    for (; i < E; i += gridDim.x * blockDim.x) {
        int row, col;
        if (i32mode) { row = e[i];     col = e[E + i]; }
        else         { row = e[2 * i]; col = e[2 * E + 2 * i]; }
        if ((unsigned)row < (unsigned)N && (unsigned)col < (unsigned)N)
            atomicOr(&mask[(size_t)row * nw + (col >> 5)], 1u << (col & 31));
    }
}

// ---------------------------------------------------------------------------
// fp32 -> bf16 conversion: x (1M), Wq|Wk|Wv fused (192K), Wp (128K) elems.
// ---------------------------------------------------------------------------
__global__ __launch_bounds__(256) void convert_kernel(
    const float* __restrict__ x,
    const float* __restrict__ Wq, const float* __restrict__ Wk,
    const float* __restrict__ Wv, const float* __restrict__ Wp,
    __hip_bfloat16* __restrict__ xb, __hip_bfloat16* __restrict__ wqkvb,
    __hip_bfloat16* __restrict__ wpb)
{
    int i = blockIdx.x * blockDim.x + threadIdx.x;   // 0 .. 344063
    const float4* src; __hip_bfloat16* dst;
    int j = i - 262144;
    if (i < 262144)      { src = (const float4*)x  + i;          dst = xb    + 4 * (size_t)i; }
    else if (j < 16384)  { src = (const float4*)Wq + j;          dst = wqkvb + 4 * (size_t)j; }
    else if (j < 32768)  { src = (const float4*)Wk + (j - 16384); dst = wqkvb + 4 * (size_t)j; }
    else if (j < 49152)  { src = (const float4*)Wv + (j - 32768); dst = wqkvb + 4 * (size_t)j; }
    else                 { src = (const float4*)Wp + (j - 49152); dst = wpb   + 4 * (size_t)(j - 49152); }
    float4 f = *src;
    dst[0] = __float2bfloat16(f.x);
    dst[1] = __float2bfloat16(f.y);
    dst[2] = __float2bfloat16(f.z);
    dst[3] = __float2bfloat16(f.w);
}

// ---------------------------------------------------------------------------
// QKV MFMA GEMM: [4096 x 256] bf16 @ Wqkv^T [768 x 256] bf16 -> q|k|v bf16.
// Block = 4 waves; wave = 32 rows x 64 cols (2 A-frags x 4 B-frags). No LDS.
// ---------------------------------------------------------------------------
__global__ __launch_bounds__(256) void qkv_mfma_kernel(
    const __hip_bfloat16* __restrict__ xb,
    const __hip_bfloat16* __restrict__ wqkvb,
    const float* __restrict__ bq, const float* __restrict__ bk,
    const float* __restrict__ bv,
    __hip_bfloat16* __restrict__ q, __hip_bfloat16* __restrict__ k,
    __hip_bfloat16* __restrict__ v)
{
    int t  = threadIdx.x;
    int wv = t >> 6, l = t & 63, lr = l & 15, lk = l >> 4;
    int m0  = blockIdx.x * 128 + wv * 32;
    int n0f = blockIdx.y * 64;                   // fused col base (0..704)

    f32x4 acc[2][4] = {};
    const short8* a0p = (const short8*)(xb + (size_t)(m0 + lr) * 256 + lk * 8);
    const short8* a1p = (const short8*)(xb + (size_t)(m0 + 16 + lr) * 256 + lk * 8);
    const short8* wp_ = (const short8*)(wqkvb + (size_t)(n0f + lr) * 256 + lk * 8);

    #pragma unroll
    for (int kk = 0; kk < 8; kk++) {
        short8 a0 = a0p[kk * 4];                 // +32 bf16 per k-step = 4 short8
        short8 a1 = a1p[kk * 4];
        #pragma unroll
        for (int j = 0; j < 4; j++) {
            short8 b = wp_[(size_t)j * 16 * 32 + kk * 4];   // +16 rows = 16*256 bf16
            acc[0][j] = __builtin_amdgcn_mfma_f32_16x16x32_bf16(a0, b, acc[0][j], 0, 0, 0);
            acc[1][j] = __builtin_amdgcn_mfma_f32_16x16x32_bf16(a1, b, acc[1][j], 0, 0, 0);
        }
    }

    int which = n0f >> 8;                        // 0=q 1=k 2=v
    int ncl   = n0f & 255;
    const float* bias = (which == 0) ? bq : (which == 1) ? bk : bv;
    __hip_bfloat16* T = (which == 0) ? q  : (which == 1) ? k  : v;

    #pragma unroll
    for (int i2 = 0; i2 < 2; i2++)
        #pragma unroll
        for (int j = 0; j < 4; j++)
            #pragma unroll
            for (int r = 0; r < 4; r++) {
                int grow = m0 + i2 * 16 + lk * 4 + r;
                int gc   = ncl + j * 16 + lr;
                T[(size_t)grow * 256 + gc] = __float2bfloat16(acc[i2][j][r] + bias[gc]);
            }
}

// ---------------------------------------------------------------------------
// Final MFMA GEMM: out = [xb | yb] @ Wp^T + bp, K=512, fp32 out.
// Block = 4 waves; wave = 16 rows x 64 cols. Grid (64, 4) = 256 blocks.
// ---------------------------------------------------------------------------
__global__ __launch_bounds__(256) void final_mfma_kernel(
    const __hip_bfloat16* __restrict__ xb, const __hip_bfloat16* __restrict__ yb,
    const __hip_bfloat16* __restrict__ wpb, const float* __restrict__ bp,
    float* __restrict__ out)
{
    int t  = threadIdx.x;
    int wv = t >> 6, l = t & 63, lr = l & 15, lk = l >> 4;
    int m0 = blockIdx.x * 64 + wv * 16;
    int n0 = blockIdx.y * 64;

    f32x4 acc[4] = {};
    const short8* axp = (const short8*)(xb + (size_t)(m0 + lr) * 256 + lk * 8);
    const short8* ayp = (const short8*)(yb + (size_t)(m0 + lr) * 256 + lk * 8);
    const short8* wp_ = (const short8*)(wpb + (size_t)(n0 + lr) * 512 + lk * 8);

    #pragma unroll
    for (int kk = 0; kk < 16; kk++) {
        short8 a = (kk < 8) ? axp[kk * 4] : ayp[(kk - 8) * 4];
        #pragma unroll
        for (int j = 0; j < 4; j++) {
            short8 b = wp_[(size_t)j * 16 * 64 + kk * 4];   // +16 rows = 16*512 bf16
            acc[j] = __builtin_amdgcn_mfma_f32_16x16x32_bf16(a, b, acc[j], 0, 0, 0);
        }
    }

    #pragma unroll
    for (int j = 0; j < 4; j++)
        #pragma unroll
        for (int r = 0; r < 4; r++) {
            int grow = m0 + lk * 4 + r;
            int gc   = n0 + j * 16 + lr;
            out[(size_t)grow * 256 + gc] = acc[j][r] + bp[gc];
        }
}

// ---------------------------------------------------------------------------
// Sparse masked attention, bf16 K/V/Q, zero in-loop syncthreads.
// One block / query row; thread roles (h = t>>5, jl = t&31).
// ---------------------------------------------------------------------------
__global__ __launch_bounds__(256) void attn_kernel(
    const unsigned* __restrict__ mask,
    const u16* __restrict__ qb, const u16* __restrict__ kb,
    const u16* __restrict__ vb, __hip_bfloat16* __restrict__ yb, int N)
{
    __shared__ int cols[MAXC];
    __shared__ int wtot[2];

    int n    = blockIdx.x;
    int t    = threadIdx.x;
    int lane = t & 63;
    int wv   = t >> 6;
    int nw   = N >> 5;                  // 128

    // ---- compact mask row (deterministic, sorted) ----
    unsigned word = 0; int pc = 0;
    if (t < nw) { word = mask[(size_t)n * nw + t]; pc = __popc(word); }
    int scan = pc;
    #pragma unroll
    for (int o = 1; o < 64; o <<= 1) {
        int other = __shfl_up(scan, o, 64);
        if (lane >= o) scan += other;
    }
    if (wv < 2 && lane == 63) wtot[wv] = scan;
    __syncthreads();
    if (t < nw) {
        int off = (wv == 1 ? wtot[0] : 0) + scan - pc;
        unsigned w = word;
        while (w && off < MAXC) {
            int b = __ffs(w) - 1;
            w &= w - 1;
            cols[off++] = (t << 5) + b;
        }
    }
    int cnt = wtot[0] + wtot[1];
    if (cnt > MAXC) cnt = MAXC;
    __syncthreads();

    int h  = t >> 5;
    int jl = t & 31;

    // q for this head into registers (exact bf16->f32)
    float qreg[32];
    const short8* qp = (const short8*)(qb + (size_t)n * 256 + h * 32);
    #pragma unroll
    for (int i = 0; i < 4; i++) {
        short8 s = qp[i];
        #pragma unroll
        for (int e = 0; e < 8; e++) qreg[i * 8 + e] = b2f((u16)s[e]);
    }

    const float scale = 0.17677669529663687f;   // 1/sqrt(32)
    float mx = -1e30f, lsm = 0.f, acc = 0.f;

    for (int c0 = 0; c0 < cnt; c0 += CHUNK) {
        int cc = min(CHUNK, cnt - c0);
        // --- score for neighbor jl of this chunk ---
        float s_val = -1e30f;
        if (jl < cc) {
            int col = cols[c0 + jl];
            const short8* kp = (const short8*)(kb + (size_t)col * 256 + h * 32);
            float sa = 0.f;
            #pragma unroll
            for (int i = 0; i < 4; i++) {
                short8 s = kp[i];
                #pragma unroll
                for (int e = 0; e < 8; e++)
                    sa = fmaf(b2f((u16)s[e]), qreg[i * 8 + e], sa);
            }
            s_val = sa * scale;
        }
        // --- chunk-level online softmax merge (width-32 group) ---
        float cm = s_val;
        #pragma unroll
        for (int o = 16; o > 0; o >>= 1) cm = fmaxf(cm, __shfl_xor(cm, o, 32));
        float mnew = fmaxf(mx, cm);
        float f = __expf(mx - mnew);
        float w = (jl < cc) ? __expf(s_val - mnew) : 0.f;
        float ls = w;
        #pragma unroll
        for (int o = 16; o > 0; o >>= 1) ls += __shfl_xor(ls, o, 32);
        lsm = lsm * f + ls;
        mx  = mnew;

        // --- V accumulation: w broadcast by shuffle, coalesced bf16 reads ---
        acc *= f;
        int j = 0;
        for (; j + 4 <= cc; j += 4) {
            float v0 = b2f(vb[(size_t)cols[c0 + j + 0] * 256 + t]);
            float v1 = b2f(vb[(size_t)cols[c0 + j + 1] * 256 + t]);
            float v2 = b2f(vb[(size_t)cols[c0 + j + 2] * 256 + t]);
            float v3 = b2f(vb[(size_t)cols[c0 + j + 3] * 256 + t]);
            acc = fmaf(__shfl(w, j + 0, 32), v0, acc);
            acc = fmaf(__shfl(w, j + 1, 32), v1, acc);
            acc = fmaf(__shfl(w, j + 2, 32), v2, acc);
            acc = fmaf(__shfl(w, j + 3, 32), v3, acc);
        }
        for (; j < cc; j++)
            acc = fmaf(__shfl(w, j, 32), b2f(vb[(size_t)cols[c0 + j] * 256 + t]), acc);
    }

    yb[(size_t)n * 256 + t] = __float2bfloat16((cnt > 0) ? acc / lsm : 0.f);
}

// ---------------------------------------------------------------------------
extern "C" void kernel_launch(void* const* d_in, const int* in_sizes, int n_in,
                              void* d_out, int out_size, void* d_ws, size_t ws_size,
                              hipStream_t stream) {
    const float* x  = (const float*)d_in[0];
    const int*   ei = (const int*)d_in[1];
    const float* Wq = (const float*)d_in[2];
    const float* bq = (const float*)d_in[3];
    const float* Wk = (const float*)d_in[4];
    const float* bk = (const float*)d_in[5];
    const float* Wv = (const float*)d_in[6];
    const float* bv = (const float*)d_in[7];
    const float* Wp = (const float*)d_in[8];
    const float* bp = (const float*)d_in[9];
    float* out = (float*)d_out;

    const int D = 256;
    int N = in_sizes[0] / D;       // 4096
    int E = in_sizes[1] / 2;       // 135168

    size_t maskB = (size_t)N * (N >> 5) * sizeof(unsigned);   // 2 MB
    char* ws = (char*)d_ws;
    unsigned* mask = (unsigned*)ws;
    int* flag = (int*)(ws + maskB);
    __hip_bfloat16* xb    = (__hip_bfloat16*)(ws + maskB + 256);
    __hip_bfloat16* qbb   = xb  + (size_t)N * D;
    __hip_bfloat16* kbb   = qbb + (size_t)N * D;
    __hip_bfloat16* vbb   = kbb + (size_t)N * D;
    __hip_bfloat16* ybb   = vbb + (size_t)N * D;
    __hip_bfloat16* wqkvb = ybb + (size_t)N * D;
    __hip_bfloat16* wpb   = wqkvb + 768 * 256;

    int n16 = (int)((maskB + 256) / 16);
    clear_kernel<<<512, 256, 0, stream>>>((uint4*)ws, n16);
    detect_i64_kernel<<<256, 256, 0, stream>>>(ei, E, flag);
    scatter_edges_kernel<<<256, 256, 0, stream>>>(ei, E, N, mask, flag);

    convert_kernel<<<1344, 256, 0, stream>>>(x, Wq, Wk, Wv, Wp, xb, wqkvb, wpb);

    dim3 gq(N / 128, 12);
    qkv_mfma_kernel<<<gq, 256, 0, stream>>>(xb, wqkvb, bq, bk, bv, qbb, kbb, vbb);

    attn_kernel<<<N, 256, 0, stream>>>(mask, (const u16*)qbb, (const u16*)kbb,
                                       (const u16*)vbb, ybb, N);

    dim3 gf(N / 64, 4);
    final_mfma_kernel<<<gf, 256, 0, stream>>>(xb, ybb, wpb, bp, out);
}

// Round 5
// 64.861 us; speedup vs baseline: 2.7799x; 1.4249x over previous
//
#include <hip/hip_runtime.h>
#include <hip/hip_bf16.h>

typedef unsigned short u16;
typedef __attribute__((ext_vector_type(8))) short short8;   // 8 bf16 = 4 VGPR
typedef __attribute__((ext_vector_type(4))) float f32x4;

#define MAXC 512
#define SC_BLOCKS 128     // scatter role blocks in fused kernel 2
#define CLR_BLOCKS 256    // clear role blocks in prep kernel
#define DET_BLOCKS 64     // detect role blocks in prep kernel

__device__ __forceinline__ float b2f(u16 b) {
    return __uint_as_float(((unsigned)b) << 16);
}
// fp32 -> bf16 round-to-nearest-even (same result as __float2bfloat16 for
// normal finite inputs; all our data is small gaussians)
__device__ __forceinline__ u16 f2b(float f) {
    unsigned u = __float_as_uint(f);
    return (u16)((u + 0x7FFFu + ((u >> 16) & 1u)) >> 16);
}
__device__ __forceinline__ short8 load_cvt8(const float* __restrict__ p) {
    float4 f0 = *(const float4*)p;
    float4 f1 = *(const float4*)(p + 4);
    short8 r;
    r[0] = (short)f2b(f0.x); r[1] = (short)f2b(f0.y);
    r[2] = (short)f2b(f0.z); r[3] = (short)f2b(f0.w);
    r[4] = (short)f2b(f1.x); r[5] = (short)f2b(f1.y);
    r[6] = (short)f2b(f1.z); r[7] = (short)f2b(f1.w);
    return r;
}

// ---------------------------------------------------------------------------
// K1 prep: blocks [0,256) clear the 2MB mask; blocks [256,320) scan the edge
// buffer's odd int32 words and write per-block partial ORs to orbuf[0..63]
// (plain stores -> no pre-cleared flag needed; orbuf fully rewritten each
// call -> deterministic). orbuf==0 everywhere <=> edge buffer is int64.
// ---------------------------------------------------------------------------
__global__ __launch_bounds__(256) void prep_kernel(
    const int* __restrict__ e, int E,
    uint4* __restrict__ maskv, int mask16, unsigned* __restrict__ orbuf)
{
    int b = blockIdx.x, t = threadIdx.x;
    if (b < CLR_BLOCKS) {
        uint4 z = {0u, 0u, 0u, 0u};
        for (int i = b * 256 + t; i < mask16; i += CLR_BLOCKS * 256) maskv[i] = z;
    } else {
        int bb = b - CLR_BLOCKS;
        unsigned acc = 0;
        for (int i = bb * 256 + t; i < E; i += DET_BLOCKS * 256)
            acc |= (unsigned)e[2 * i + 1];
        __shared__ unsigned red[4];
        #pragma unroll
        for (int o = 32; o > 0; o >>= 1) acc |= __shfl_xor(acc, o, 64);
        if ((t & 63) == 0) red[t >> 6] = acc;
        __syncthreads();
        if (t == 0) orbuf[bb] = red[0] | red[1] | red[2] | red[3];
    }
}

// ---------------------------------------------------------------------------
// K2 fused: blocks [0,128) scatter edges into the mask bitmask (atomicOr
// dedups, idempotent -> deterministic); blocks [128,512) run the QKV MFMA
// GEMM [4096x256]@Wqkv^T with on-the-fly fp32->bf16 conversion.
// W tile (64 out-cols x 256 k) converted once per block into LDS bf16
// (row pad +8 -> 2-way bank aliasing only, free); A fragments converted
// per-wave from fp32 (16B-contiguous per lane).
// ---------------------------------------------------------------------------
__global__ __launch_bounds__(256) void scatter_qkv_kernel(
    const int* __restrict__ e, int E, int N,
    unsigned* __restrict__ mask, const unsigned* __restrict__ orbuf,
    const float* __restrict__ x,
    const float* __restrict__ Wq, const float* __restrict__ Wk,
    const float* __restrict__ Wv,
    const float* __restrict__ bq, const float* __restrict__ bk,
    const float* __restrict__ bv,
    u16* __restrict__ q, u16* __restrict__ k, u16* __restrict__ v)
{
    __shared__ u16 Wl[64][264];
    int t = threadIdx.x;

    if (blockIdx.x < SC_BLOCKS) {
        unsigned oo = orbuf[t & 63];
        #pragma unroll
        for (int o = 32; o > 0; o >>= 1) oo |= __shfl_xor(oo, o, 64);
        bool i32mode = (oo != 0);
        int nw = N >> 5;
        for (int i = blockIdx.x * 256 + t; i < E; i += SC_BLOCKS * 256) {
            int row, col;
            if (i32mode) { row = e[i];     col = e[E + i]; }
            else         { row = e[2 * i]; col = e[2 * E + 2 * i]; }
            if ((unsigned)row < (unsigned)N && (unsigned)col < (unsigned)N)
                atomicOr(&mask[(size_t)row * nw + (col >> 5)], 1u << (col & 31));
        }
        return;
    }

    int bid = blockIdx.x - SC_BLOCKS;          // 0..383
    int bx = bid & 31, by = bid >> 5;          // 32 row tiles x 12 col tiles
    int which = by >> 2;                       // 0=q 1=k 2=v
    int ncl = (by & 3) * 64;                   // col base within 256
    const float* Ws   = (which == 0) ? Wq : (which == 1) ? Wk : Wv;
    const float* bias = (which == 0) ? bq : (which == 1) ? bk : bv;
    u16*         T    = (which == 0) ? q  : (which == 1) ? k  : v;

    // stage W tile -> LDS bf16
    for (int s = t; s < 4096; s += 256) {
        int r  = s >> 6;            // 0..63
        int c4 = (s & 63) << 2;     // 0..252
        float4 f = *(const float4*)&Ws[(size_t)(ncl + r) * 256 + c4];
        Wl[r][c4 + 0] = f2b(f.x); Wl[r][c4 + 1] = f2b(f.y);
        Wl[r][c4 + 2] = f2b(f.z); Wl[r][c4 + 3] = f2b(f.w);
    }
    __syncthreads();

    int wv = t >> 6, l = t & 63, lr = l & 15, lk = l >> 4;
    int m0 = bx * 128 + wv * 32;
    f32x4 acc[2][4] = {};
    const float* a0b = x + (size_t)(m0 + lr) * 256 + lk * 8;
    const float* a1b = a0b + 16 * 256;

    #pragma unroll
    for (int kk = 0; kk < 8; kk++) {
        short8 a0 = load_cvt8(a0b + kk * 32);
        short8 a1 = load_cvt8(a1b + kk * 32);
        #pragma unroll
        for (int j = 0; j < 4; j++) {
            short8 b = *(const short8*)&Wl[j * 16 + lr][lk * 8 + kk * 32];
            acc[0][j] = __builtin_amdgcn_mfma_f32_16x16x32_bf16(a0, b, acc[0][j], 0, 0, 0);
            acc[1][j] = __builtin_amdgcn_mfma_f32_16x16x32_bf16(a1, b, acc[1][j], 0, 0, 0);
        }
    }

    #pragma unroll
    for (int i2 = 0; i2 < 2; i2++)
        #pragma unroll
        for (int j = 0; j < 4; j++)
            #pragma unroll
            for (int r = 0; r < 4; r++) {
                int grow = m0 + i2 * 16 + lk * 4 + r;
                int gc   = ncl + j * 16 + lr;
                T[(size_t)grow * 256 + gc] = f2b(acc[i2][j][r] + bias[gc]);
            }
}

// ---------------------------------------------------------------------------
// K3 sparse masked attention, CHUNK=64 (two dots per thread), zero in-loop
// syncthreads. One block / query row; roles (h = t>>5, jl = t&31).
// ---------------------------------------------------------------------------
__device__ __forceinline__ float dot32(const u16* __restrict__ kp,
                                       const float* __restrict__ qreg) {
    float sa = 0.f;
    #pragma unroll
    for (int i = 0; i < 4; i++) {
        short8 s = ((const short8*)kp)[i];
        #pragma unroll
        for (int e2 = 0; e2 < 8; e2++)
            sa = fmaf(b2f((u16)s[e2]), qreg[i * 8 + e2], sa);
    }
    return sa;
}

__global__ __launch_bounds__(256) void attn_kernel(
    const unsigned* __restrict__ mask,
    const u16* __restrict__ qb, const u16* __restrict__ kb,
    const u16* __restrict__ vb, u16* __restrict__ yb, int N)
{
    __shared__ int cols[MAXC];
    __shared__ int wtot[2];

    int n = blockIdx.x, t = threadIdx.x;
    int lane = t & 63, wv = t >> 6, nw = N >> 5;

    // ---- compact mask row (deterministic, sorted) ----
    unsigned word = 0; int pc = 0;
    if (t < nw) { word = mask[(size_t)n * nw + t]; pc = __popc(word); }
    int scan = pc;
    #pragma unroll
    for (int o = 1; o < 64; o <<= 1) {
        int ot = __shfl_up(scan, o, 64);
        if (lane >= o) scan += ot;
    }
    if (wv < 2 && lane == 63) wtot[wv] = scan;
    __syncthreads();
    if (t < nw) {
        int off = (wv == 1 ? wtot[0] : 0) + scan - pc;
        unsigned w = word;
        while (w && off < MAXC) {
            int b = __ffs(w) - 1;
            w &= w - 1;
            cols[off++] = (t << 5) + b;
        }
    }
    int cnt = wtot[0] + wtot[1];
    if (cnt > MAXC) cnt = MAXC;
    __syncthreads();

    int h = t >> 5, jl = t & 31;
    float qreg[32];
    const short8* qp = (const short8*)(qb + (size_t)n * 256 + h * 32);
    #pragma unroll
    for (int i = 0; i < 4; i++) {
        short8 s = qp[i];
        #pragma unroll
        for (int e2 = 0; e2 < 8; e2++) qreg[i * 8 + e2] = b2f((u16)s[e2]);
    }

    const float scale = 0.17677669529663687f;   // 1/sqrt(32)
    float mx = -1e30f, lsm = 0.f, acc = 0.f;

    for (int c0 = 0; c0 < cnt; c0 += 64) {
        int cc = min(64, cnt - c0);
        float s0 = -1e30f, s1 = -1e30f;
        if (jl < cc)
            s0 = dot32(kb + (size_t)cols[c0 + jl] * 256 + h * 32, qreg) * scale;
        if (jl + 32 < cc)
            s1 = dot32(kb + (size_t)cols[c0 + jl + 32] * 256 + h * 32, qreg) * scale;

        float cm = fmaxf(s0, s1);
        #pragma unroll
        for (int o = 16; o > 0; o >>= 1) cm = fmaxf(cm, __shfl_xor(cm, o, 32));
        float mnew = fmaxf(mx, cm);
        float f  = __expf(mx - mnew);
        float w0 = (jl < cc)      ? __expf(s0 - mnew) : 0.f;
        float w1 = (jl + 32 < cc) ? __expf(s1 - mnew) : 0.f;
        float ls = w0 + w1;
        #pragma unroll
        for (int o = 16; o > 0; o >>= 1) ls += __shfl_xor(ls, o, 32);
        lsm = lsm * f + ls;
        mx  = mnew;
        acc *= f;

        int e1 = min(cc, 32);
        int j = 0;
        for (; j + 4 <= e1; j += 4) {
            float v0 = b2f(vb[(size_t)cols[c0 + j + 0] * 256 + t]);
            float v1 = b2f(vb[(size_t)cols[c0 + j + 1] * 256 + t]);
            float v2 = b2f(vb[(size_t)cols[c0 + j + 2] * 256 + t]);
            float v3 = b2f(vb[(size_t)cols[c0 + j + 3] * 256 + t]);
            acc = fmaf(__shfl(w0, j + 0, 32), v0, acc);
            acc = fmaf(__shfl(w0, j + 1, 32), v1, acc);
            acc = fmaf(__shfl(w0, j + 2, 32), v2, acc);
            acc = fmaf(__shfl(w0, j + 3, 32), v3, acc);
        }
        for (; j < e1; j++)
            acc = fmaf(__shfl(w0, j, 32), b2f(vb[(size_t)cols[c0 + j] * 256 + t]), acc);
        for (j = 32; j + 4 <= cc; j += 4) {
            float v0 = b2f(vb[(size_t)cols[c0 + j + 0] * 256 + t]);
            float v1 = b2f(vb[(size_t)cols[c0 + j + 1] * 256 + t]);
            float v2 = b2f(vb[(size_t)cols[c0 + j + 2] * 256 + t]);
            float v3 = b2f(vb[(size_t)cols[c0 + j + 3] * 256 + t]);
            acc = fmaf(__shfl(w1, j - 32, 32), v0, acc);
            acc = fmaf(__shfl(w1, j - 31, 32), v1, acc);
            acc = fmaf(__shfl(w1, j - 30, 32), v2, acc);
            acc = fmaf(__shfl(w1, j - 29, 32), v3, acc);
        }
        for (; j < cc; j++)
            acc = fmaf(__shfl(w1, j - 32, 32), b2f(vb[(size_t)cols[c0 + j] * 256 + t]), acc);
    }

    yb[(size_t)n * 256 + t] = f2b((cnt > 0) ? acc / lsm : 0.f);
}

// ---------------------------------------------------------------------------
// K4 final MFMA GEMM: out = [x | y] @ Wp^T + bp, K=512, fp32 out.
// Wp tile (64 out-cols x 512 k) fp32->bf16 into LDS once per block;
// A: x half converted on the fly, y half read bf16 directly.
// ---------------------------------------------------------------------------
__global__ __launch_bounds__(256) void final_kernel(
    const float* __restrict__ x, const u16* __restrict__ yb,
    const float* __restrict__ Wp, const float* __restrict__ bp,
    float* __restrict__ out)
{
    __shared__ u16 Wl[64][520];
    int t = threadIdx.x;
    int n0 = blockIdx.y * 64;

    for (int s = t; s < 8192; s += 256) {
        int r  = s >> 7;             // 0..63
        int c4 = (s & 127) << 2;     // 0..508
        float4 f = *(const float4*)&Wp[(size_t)(n0 + r) * 512 + c4];
        Wl[r][c4 + 0] = f2b(f.x); Wl[r][c4 + 1] = f2b(f.y);
        Wl[r][c4 + 2] = f2b(f.z); Wl[r][c4 + 3] = f2b(f.w);
    }
    __syncthreads();

    int wv = t >> 6, l = t & 63, lr = l & 15, lk = l >> 4;
    int m0 = blockIdx.x * 64 + wv * 16;
    f32x4 acc[4] = {};
    const float* axb = x  + (size_t)(m0 + lr) * 256 + lk * 8;
    const u16*   ayb = yb + (size_t)(m0 + lr) * 256 + lk * 8;

    #pragma unroll
    for (int kk = 0; kk < 16; kk++) {
        short8 a;
        if (kk < 8) a = load_cvt8(axb + kk * 32);
        else        a = *(const short8*)(ayb + (kk - 8) * 32);
        #pragma unroll
        for (int j = 0; j < 4; j++) {
            short8 b = *(const short8*)&Wl[j * 16 + lr][lk * 8 + kk * 32];
            acc[j] = __builtin_amdgcn_mfma_f32_16x16x32_bf16(a, b, acc[j], 0, 0, 0);
        }
    }

    #pragma unroll
    for (int j = 0; j < 4; j++)
        #pragma unroll
        for (int r = 0; r < 4; r++) {
            int grow = m0 + lk * 4 + r;
            int gc   = n0 + j * 16 + lr;
            out[(size_t)grow * 256 + gc] = acc[j][r] + bp[gc];
        }
}

// ---------------------------------------------------------------------------
extern "C" void kernel_launch(void* const* d_in, const int* in_sizes, int n_in,
                              void* d_out, int out_size, void* d_ws, size_t ws_size,
                              hipStream_t stream) {
    const float* x  = (const float*)d_in[0];
    const int*   ei = (const int*)d_in[1];
    const float* Wq = (const float*)d_in[2];
    const float* bq = (const float*)d_in[3];
    const float* Wk = (const float*)d_in[4];
    const float* bk = (const float*)d_in[5];
    const float* Wv = (const float*)d_in[6];
    const float* bv = (const float*)d_in[7];
    const float* Wp = (const float*)d_in[8];
    const float* bp = (const float*)d_in[9];
    float* out = (float*)d_out;

    const int D = 256;
    int N = in_sizes[0] / D;       // 4096
    int E = in_sizes[1] / 2;       // 135168

    size_t maskB = (size_t)N * (N >> 5) * sizeof(unsigned);   // 2 MB
    char* ws = (char*)d_ws;
    unsigned* mask  = (unsigned*)ws;
    unsigned* orbuf = (unsigned*)(ws + maskB);                // 64 words
    u16* qbb = (u16*)(ws + maskB + 256);
    u16* kbb = qbb + (size_t)N * D;
    u16* vbb = kbb + (size_t)N * D;
    u16* ybb = vbb + (size_t)N * D;

    prep_kernel<<<CLR_BLOCKS + DET_BLOCKS, 256, 0, stream>>>(
        ei, E, (uint4*)ws, (int)(maskB / 16), orbuf);

    scatter_qkv_kernel<<<SC_BLOCKS + 384, 256, 0, stream>>>(
        ei, E, N, mask, orbuf, x, Wq, Wk, Wv, bq, bk, bv, qbb, kbb, vbb);

    attn_kernel<<<N, 256, 0, stream>>>(mask, qbb, kbb, vbb, ybb, N);

    dim3 gf(N / 64, 4);
    final_kernel<<<gf, 256, 0, stream>>>(x, ybb, Wp, bp, out);
}